// Round 2
// baseline (752.344 us; speedup 1.0000x reference)
//
#include <hip/hip_runtime.h>
#include <cstdint>
#include <cstddef>

// MossVLSelfAttention fused pipeline, MI355X round 2.
// Changes vs round 1:
//  - k_flash: barrier-free key-split flash. Block = one 16-row q-tile, 4 waves
//    stride over 64-key tiles reading K/V B-frags DIRECTLY from global (L2-fits,
//    2MB/head-pair), merge partial (m,l,O) once at end via LDS arena.
//    XCD-bijective swizzle pins each XCD to one kv-head pair.
//  - k_gemm_x3: m97-style global_load_lds staging (single 32KB LDS buffer,
//    2 barriers/K-step) + split-K with atomicAdd epilogue (memset-zeroed C).
// Precision unchanged: bf16x3 everywhere, fp32 softmax/accum.
// Workspace layout (byte offsets, ~146 MB):
//   0   hid_hi[T][2048]      8M   hid_lo
//   16M wqkvT_hi[4096][2048] 32M  wqkvT_lo
//   48M woT_hi[2048][2048]   56M  woT_lo
//   64M qkv_f32[T][4096]
//   96M q_hi[T][16][128]     104M q_lo
//   112M k_hi[T][8][128]     116M k_lo
//   120M vT_hi[8][128][T]    124M vT_lo
//   128M attn_hi[T][2048]    136M attn_lo
//   144M trig[T][64] float2

#define C_NH 16
#define C_NKV 8
#define C_DH 128
#define C_HID 2048
#define C_NQKV 4096

typedef unsigned short u16;
typedef __attribute__((ext_vector_type(8))) short short8;
typedef __attribute__((ext_vector_type(4))) float f32x4;

__device__ __forceinline__ u16 f2bf(float x) {
  uint32_t u = __float_as_uint(x);
  u += 0x7FFFu + ((u >> 16) & 1u);   // round-to-nearest-even
  return (u16)(u >> 16);
}
__device__ __forceinline__ float bf2f(u16 h) {
  return __uint_as_float(((uint32_t)h) << 16);
}
__device__ __forceinline__ void bsplit(float x, u16& hi, u16& lo) {
  u16 h = f2bf(x);
  hi = h;
  lo = f2bf(x - bf2f(h));             // residual: ~16 mantissa bits total
}

// async global->LDS, 16B per lane; LDS dest is wave-uniform base + lane*16.
__device__ __forceinline__ void gload16(const void* g, void* l) {
  __builtin_amdgcn_global_load_lds(
      (const __attribute__((address_space(1))) void*)g,
      (__attribute__((address_space(3))) void*)l, 16, 0, 0);
}

// ---------------- trig table ---------------------------------------------------
__global__ void k_trig(const int* __restrict__ pos, float2* __restrict__ tab) {
  int t = blockIdx.x;
  int j = threadIdx.x;                // 64 threads
  float inv = 1.0f / powf(1.0e6f, (float)j * (1.0f / 64.0f));
  float ang = (float)pos[t] * inv;
  tab[t * 64 + j] = make_float2(cosf(ang), sinf(ang));
}

// ---------------- plain split: f32[n] -> hi/lo bf16 ---------------------------
struct __align__(8) U4 { u16 a, b, c, d; };

__global__ void k_split(const float* __restrict__ in, u16* __restrict__ hi,
                        u16* __restrict__ lo, int n) {
  int i = (blockIdx.x * 256 + threadIdx.x) * 4;
  if (i >= n) return;
  float4 x = *(const float4*)(in + i);
  U4 hv, lv;
  bsplit(x.x, hv.a, lv.a);
  bsplit(x.y, hv.b, lv.b);
  bsplit(x.z, hv.c, lv.c);
  bsplit(x.w, hv.d, lv.d);
  *(U4*)(hi + i) = hv;
  *(U4*)(lo + i) = lv;
}

// ---------------- split + transpose: in[K][N] -> hi/lo[N][K] ------------------
__global__ void k_split_tr(const float* __restrict__ in, u16* __restrict__ hi,
                           u16* __restrict__ lo, int K, int N) {
  __shared__ float t[64][65];
  const int kb = blockIdx.y * 64, nb = blockIdx.x * 64;
  const int tid = threadIdx.x;
  for (int i = tid; i < 4096; i += 256) {
    int r = i >> 6, c = i & 63;
    t[r][c] = in[(size_t)(kb + r) * N + nb + c];
  }
  __syncthreads();
  for (int i = tid; i < 4096; i += 256) {
    int r = i >> 6, c = i & 63;       // r = n-local, c = k-local
    u16 h, l;
    bsplit(t[c][r], h, l);
    size_t o = (size_t)(nb + r) * K + kb + c;
    hi[o] = h;
    lo[o] = l;
  }
}

// ---------------- bf16x3 GEMM: C[M][N] += A[M][K] * B^T[N][K] -----------------
// m97 structure: 128x128 tile, 4 waves, BK=32, single-buffer LDS staged via
// global_load_lds width=16, 2 barriers per K-step. Split-K over blockIdx.z
// with f32 atomicAdd epilogue (C must be zeroed before).
__global__ __launch_bounds__(256, 2)
void k_gemm_x3(const u16* __restrict__ Ah, const u16* __restrict__ Al,
               const u16* __restrict__ Bh, const u16* __restrict__ Bl,
               float* __restrict__ C, int M, int N, int K, int klen) {
  __shared__ u16 lds[4][4096];          // [Ah,Al,Bh,Bl][128 rows x 32 k]
  const int tid = threadIdx.x;
  const int lane = tid & 63;
  const int wv = tid >> 6;
  const int wr = wv >> 1, wc = wv & 1;
  const int mb = blockIdx.y * 128, nb = blockIdx.x * 128;
  const int k0 = blockIdx.z * klen;
  const int ra = lane & 15, ko = (lane >> 4) * 8;

  f32x4 acc[4][4] = {};
  const int nk = klen >> 5;
  const int rS = lane >> 2, cS = (lane & 3) * 8;   // staging row/col within chunk

  for (int kt = 0; kt < nk; ++kt) {
    const int kb = k0 + kt * 32;
    __syncthreads();                    // previous compute done, LDS reusable
#pragma unroll
    for (int ci = 0; ci < 2; ++ci) {    // wave stages chunks 2w, 2w+1 (16 rows ea)
      int c = wv * 2 + ci;
      int row = c * 16 + rS;
      gload16(Ah + (size_t)(mb + row) * K + kb + cS, &lds[0][c * 512]);
      gload16(Al + (size_t)(mb + row) * K + kb + cS, &lds[1][c * 512]);
      gload16(Bh + (size_t)(nb + row) * K + kb + cS, &lds[2][c * 512]);
      gload16(Bl + (size_t)(nb + row) * K + kb + cS, &lds[3][c * 512]);
    }
    __syncthreads();                    // compiler drains vmcnt before barrier

    short8 a_h[4], a_l[4], b_h[4], b_l[4];
#pragma unroll
    for (int m = 0; m < 4; ++m) {
      int r = (wr * 64 + m * 16 + ra) * 32 + ko;
      a_h[m] = *(const short8*)&lds[0][r];
      a_l[m] = *(const short8*)&lds[1][r];
    }
#pragma unroll
    for (int n = 0; n < 4; ++n) {
      int r = (wc * 64 + n * 16 + ra) * 32 + ko;
      b_h[n] = *(const short8*)&lds[2][r];
      b_l[n] = *(const short8*)&lds[3][r];
    }
#pragma unroll
    for (int m = 0; m < 4; ++m)
#pragma unroll
      for (int n = 0; n < 4; ++n) {
        acc[m][n] = __builtin_amdgcn_mfma_f32_16x16x32_bf16(a_h[m], b_h[n], acc[m][n], 0, 0, 0);
        acc[m][n] = __builtin_amdgcn_mfma_f32_16x16x32_bf16(a_h[m], b_l[n], acc[m][n], 0, 0, 0);
        acc[m][n] = __builtin_amdgcn_mfma_f32_16x16x32_bf16(a_l[m], b_h[n], acc[m][n], 0, 0, 0);
      }
  }
  const int cr = mb + wr * 64 + (lane >> 4) * 4;
  const int cc = nb + wc * 64 + ra;
#pragma unroll
  for (int m = 0; m < 4; ++m)
#pragma unroll
    for (int n = 0; n < 4; ++n)
#pragma unroll
      for (int r = 0; r < 4; ++r)
        atomicAdd(&C[(size_t)(cr + m * 16 + r) * N + cc + n * 16], acc[m][n][r]);
}

// ---------------- RMSNorm + RoPE + split (q,k) / split+transpose (v) ----------
__global__ void k_normrope(const float* __restrict__ qkv, const float2* __restrict__ tab,
                           const float* __restrict__ qw, const float* __restrict__ kw,
                           u16* __restrict__ Qh, u16* __restrict__ Ql,
                           u16* __restrict__ Kh, u16* __restrict__ Kl,
                           u16* __restrict__ Vh, u16* __restrict__ Vl, int T) {
  int gw = blockIdx.x * 4 + (threadIdx.x >> 6);
  if (gw >= T * 32) return;
  int lane = threadIdx.x & 63;
  int t = gw >> 5, hd = gw & 31;
  const float* src;
  if (hd < C_NH)              src = qkv + (size_t)t * C_NQKV + hd * C_DH;
  else if (hd < C_NH + C_NKV) src = qkv + (size_t)t * C_NQKV + C_NH * C_DH + (hd - C_NH) * C_DH;
  else                        src = qkv + (size_t)t * C_NQKV + (C_NH + C_NKV) * C_DH + (hd - C_NH - C_NKV) * C_DH;
  float x1 = src[lane], x2 = src[lane + 64];

  if (hd >= C_NH + C_NKV) {   // v: split + store transposed [8][128][T]
    int vh = hd - C_NH - C_NKV;
    u16 h, l;
    bsplit(x1, h, l);
    size_t o1 = ((size_t)vh * C_DH + lane) * T + t;
    Vh[o1] = h; Vl[o1] = l;
    bsplit(x2, h, l);
    size_t o2 = ((size_t)vh * C_DH + lane + 64) * T + t;
    Vh[o2] = h; Vl[o2] = l;
    return;
  }
  float ss = x1 * x1 + x2 * x2;
  ss += __shfl_xor(ss, 1, 64);
  ss += __shfl_xor(ss, 2, 64);
  ss += __shfl_xor(ss, 4, 64);
  ss += __shfl_xor(ss, 8, 64);
  ss += __shfl_xor(ss, 16, 64);
  ss += __shfl_xor(ss, 32, 64);
  float rms = rsqrtf(ss * (1.0f / 128.0f) + 1e-6f);
  const float* w = (hd < C_NH) ? qw : kw;
  float y1 = x1 * rms * w[lane];
  float y2 = x2 * rms * w[lane + 64];
  float2 cs = tab[t * 64 + lane];
  float o1 = y1 * cs.x - y2 * cs.y;
  float o2 = y2 * cs.x + y1 * cs.y;
  u16 h, l;
  if (hd < C_NH) {
    size_t o = ((size_t)t * C_NH + hd) * C_DH + lane;
    bsplit(o1, h, l); Qh[o] = h; Ql[o] = l;
    bsplit(o2, h, l); Qh[o + 64] = h; Ql[o + 64] = l;
  } else {
    int kh = hd - C_NH;
    size_t o = ((size_t)t * C_NKV + kh) * C_DH + lane;
    bsplit(o1, h, l); Kh[o] = h; Kl[o] = l;
    bsplit(o2, h, l); Kh[o + 64] = h; Kl[o + 64] = l;
  }
}

// ---------------- causal flash attention v3 (barrier-free key-split) ----------
// Grid: 2048 flat blocks -> (h, qt) via XCD-bijective swizzle (XCD x owns
// kv-head x: 2MB K+V hi/lo working set in its 4MB L2). Block = 256 thr = 4
// waves, ONE q-tile of 16 rows; wave w handles key-tiles w, w+4, ... (KVBLK=64)
// reading K/V fragments straight from global (L2). No barriers in main loop;
// one merge at the end combines per-wave (m, l, O) through an LDS arena.
#define ARENA_B 8448                    // per-wave: max(P 2*16*76*2, O 16*132*4)
__global__ __launch_bounds__(256, 3)
void k_flash(const u16* __restrict__ Qh, const u16* __restrict__ Ql,
             const u16* __restrict__ Kg_h, const u16* __restrict__ Kg_l,
             const u16* __restrict__ Vg_h, const u16* __restrict__ Vg_l,
             u16* __restrict__ Oh, u16* __restrict__ Ol, int T) {
  __shared__ __align__(16) char arena[4][ARENA_B];
  __shared__ float Msh[4][16], Lsh[4][16];
  const int tid = threadIdx.x, lane = tid & 63, wv = tid >> 6;
  const int lm = lane & 15, lq = lane >> 4;

  const int flat = blockIdx.x;                    // 2048 blocks
  const int nid = (flat & 7) * 256 + (flat >> 3); // XCD-contiguous remap
  const int h = nid >> 7, qt = nid & 127;         // head, q-tile (16 rows)
  const int hk = h >> 1;
  const int qb = qt * 16;

  // Q fragments (A-frag: row=lm, k=kc*32+lq*8) held in registers throughout.
  short8 qfh[4], qfl[4];
#pragma unroll
  for (int kc = 0; kc < 4; ++kc) {
    size_t o = ((size_t)(qb + lm) * C_NH + h) * C_DH + kc * 32 + lq * 8;
    qfh[kc] = *(const short8*)(Qh + o);
    qfl[kc] = *(const short8*)(Ql + o);
  }
  f32x4 o_acc[8] = {};
  float m_r[4], l_r[4];
#pragma unroll
  for (int r = 0; r < 4; ++r) { m_r[r] = -1e30f; l_r[r] = 0.f; }

  u16* P = (u16*)arena[wv];             // [2][16][76] bf16 hi/lo P-exchange
  const float scale = 0.08838834764831845f;   // 1/sqrt(128)
  const int ntiles = (qt + 4) >> 2;     // ceil((16qt+16)/64)

  for (int kt = wv; kt < ntiles; kt += 4) {
    const int kvb = kt * 64;
    // ---- S = Q K^T over 64 keys (4 sub-tiles), K frags from global ----
    f32x4 s[4] = {};
#pragma unroll
    for (int nt = 0; nt < 4; ++nt) {
      const u16* kbase_h = Kg_h + ((size_t)(kvb + nt * 16 + lm) * C_NKV + hk) * C_DH + lq * 8;
      const u16* kbase_l = Kg_l + ((size_t)(kvb + nt * 16 + lm) * C_NKV + hk) * C_DH + lq * 8;
#pragma unroll
      for (int kc = 0; kc < 4; ++kc) {
        short8 bh = *(const short8*)(kbase_h + kc * 32);
        short8 bl = *(const short8*)(kbase_l + kc * 32);
        s[nt] = __builtin_amdgcn_mfma_f32_16x16x32_bf16(qfh[kc], bh, s[nt], 0, 0, 0);
        s[nt] = __builtin_amdgcn_mfma_f32_16x16x32_bf16(qfh[kc], bl, s[nt], 0, 0, 0);
        s[nt] = __builtin_amdgcn_mfma_f32_16x16x32_bf16(qfl[kc], bh, s[nt], 0, 0, 0);
      }
    }
    // ---- online softmax (row = lq*4+r, key-cols = lm + 16*nt) ----
#pragma unroll
    for (int r = 0; r < 4; ++r) {
      const int qrow = qb + lq * 4 + r;
      float sv[4];
#pragma unroll
      for (int nt = 0; nt < 4; ++nt)
        sv[nt] = (kvb + nt * 16 + lm <= qrow) ? s[nt][r] * scale : -1e30f;
      float pm = fmaxf(fmaxf(sv[0], sv[1]), fmaxf(sv[2], sv[3]));
      pm = fmaxf(pm, __shfl_xor(pm, 1, 16));
      pm = fmaxf(pm, __shfl_xor(pm, 2, 16));
      pm = fmaxf(pm, __shfl_xor(pm, 4, 16));
      pm = fmaxf(pm, __shfl_xor(pm, 8, 16));
      float mn = fmaxf(m_r[r], pm);
      float alpha = __expf(m_r[r] - mn);
      float p[4], ps = 0.f;
#pragma unroll
      for (int nt = 0; nt < 4; ++nt) { p[nt] = __expf(sv[nt] - mn); ps += p[nt]; }
      ps += __shfl_xor(ps, 1, 16);
      ps += __shfl_xor(ps, 2, 16);
      ps += __shfl_xor(ps, 4, 16);
      ps += __shfl_xor(ps, 8, 16);
      l_r[r] = l_r[r] * alpha + ps;
      m_r[r] = mn;
#pragma unroll
      for (int jb = 0; jb < 8; ++jb) o_acc[jb][r] *= alpha;
#pragma unroll
      for (int nt = 0; nt < 4; ++nt) {
        u16 ph, pl;
        bsplit(p[nt], ph, pl);
        P[0 * 1216 + (lq * 4 + r) * 76 + nt * 16 + lm] = ph;
        P[1 * 1216 + (lq * 4 + r) * 76 + nt * 16 + lm] = pl;
      }
    }
    // ---- O += P V, V frags from global-transposed [hk][d][T] ----
    short8 pa_h[2], pa_l[2];
#pragma unroll
    for (int kc2 = 0; kc2 < 2; ++kc2) {
      pa_h[kc2] = *(const short8*)&P[0 * 1216 + lm * 76 + kc2 * 32 + lq * 8];
      pa_l[kc2] = *(const short8*)&P[1 * 1216 + lm * 76 + kc2 * 32 + lq * 8];
    }
#pragma unroll
    for (int jb = 0; jb < 8; ++jb) {
      const size_t vrow = ((size_t)hk * C_DH + 16 * jb + lm) * T + kvb + lq * 8;
#pragma unroll
      for (int kc2 = 0; kc2 < 2; ++kc2) {
        short8 vh = *(const short8*)(Vg_h + vrow + kc2 * 32);
        short8 vl = *(const short8*)(Vg_l + vrow + kc2 * 32);
        o_acc[jb] = __builtin_amdgcn_mfma_f32_16x16x32_bf16(pa_h[kc2], vh, o_acc[jb], 0, 0, 0);
        o_acc[jb] = __builtin_amdgcn_mfma_f32_16x16x32_bf16(pa_h[kc2], vl, o_acc[jb], 0, 0, 0);
        o_acc[jb] = __builtin_amdgcn_mfma_f32_16x16x32_bf16(pa_l[kc2], vh, o_acc[jb], 0, 0, 0);
      }
    }
  }

  // ---- publish per-wave partials (unnormalized O, stats) ----
  float* Of = (float*)arena[wv];        // [16][132] f32, overlays P (same wave)
#pragma unroll
  for (int r = 0; r < 4; ++r) {
    if (lm == 0) { Msh[wv][lq * 4 + r] = m_r[r]; Lsh[wv][lq * 4 + r] = l_r[r]; }
#pragma unroll
    for (int jb = 0; jb < 8; ++jb)
      Of[(lq * 4 + r) * 132 + lm + 16 * jb] = o_acc[jb][r];
  }
  __syncthreads();

  // ---- merge 4 key-split partials; write bf16 hi/lo ----
  const int q = tid >> 4, d0 = (tid & 15) * 8;
  float M = fmaxf(fmaxf(Msh[0][q], Msh[1][q]), fmaxf(Msh[2][q], Msh[3][q]));
  float wgt[4], L = 0.f;
#pragma unroll
  for (int w = 0; w < 4; ++w) {
    wgt[w] = __expf(Msh[w][q] - M);
    L += wgt[w] * Lsh[w][q];
  }
  float invL = 1.0f / L;
#pragma unroll
  for (int j = 0; j < 8; ++j) {
    float o = 0.f;
#pragma unroll
    for (int w = 0; w < 4; ++w)
      o += wgt[w] * ((const float*)arena[w])[q * 132 + d0 + j];
    float val = o * invL;
    u16 hh, ll;
    bsplit(val, hh, ll);
    size_t oo = ((size_t)(qb + q) * C_NH + h) * C_DH + d0 + j;
    Oh[oo] = hh;
    Ol[oo] = ll;
  }
}

// ---------------- launch --------------------------------------------------------
extern "C" void kernel_launch(void* const* d_in, const int* in_sizes, int n_in,
                              void* d_out, int out_size, void* d_ws, size_t ws_size,
                              hipStream_t stream) {
  const int*   pos  = (const int*)d_in[0];
  const float* hid  = (const float*)d_in[1];
  const float* wqkv = (const float*)d_in[2];
  const float* qnw  = (const float*)d_in[3];
  const float* knw  = (const float*)d_in[4];
  const float* wo   = (const float*)d_in[5];
  float* out = (float*)d_out;
  const int T = in_sizes[0];                   // 2048

  char* ws = (char*)d_ws;
  const size_t MB = 1024 * 1024;
  u16*    hid_h = (u16*)(ws);
  u16*    hid_l = (u16*)(ws + 8 * MB);
  u16*    wq_h  = (u16*)(ws + 16 * MB);
  u16*    wq_l  = (u16*)(ws + 32 * MB);
  u16*    wo_h  = (u16*)(ws + 48 * MB);
  u16*    wo_l  = (u16*)(ws + 56 * MB);
  float*  qkv   = (float*)(ws + 64 * MB);
  u16*    q_h   = (u16*)(ws + 96 * MB);
  u16*    q_l   = (u16*)(ws + 104 * MB);
  u16*    k_h   = (u16*)(ws + 112 * MB);
  u16*    k_l   = (u16*)(ws + 116 * MB);
  u16*    v_h   = (u16*)(ws + 120 * MB);
  u16*    v_l   = (u16*)(ws + 124 * MB);
  u16*    at_h  = (u16*)(ws + 128 * MB);
  u16*    at_l  = (u16*)(ws + 136 * MB);
  float2* tab   = (float2*)(ws + 144 * MB);

  // zero split-K accumulation targets (atomicAdd epilogues)
  hipMemsetAsync(qkv, 0, (size_t)T * C_NQKV * sizeof(float), stream);
  hipMemsetAsync(out, 0, (size_t)T * C_HID * sizeof(float), stream);

  k_trig<<<T, 64, 0, stream>>>(pos, tab);
  k_split<<<(T * C_HID) / 1024, 256, 0, stream>>>(hid, hid_h, hid_l, T * C_HID);
  k_split_tr<<<dim3(C_NQKV / 64, C_HID / 64), 256, 0, stream>>>(wqkv, wq_h, wq_l, C_HID, C_NQKV);
  k_split_tr<<<dim3(C_HID / 64, C_HID / 64), 256, 0, stream>>>(wo, wo_h, wo_l, C_HID, C_HID);
  // QKV: M=2048 N=4096 K=2048, split-K=2 -> 1024 blocks
  k_gemm_x3<<<dim3(C_NQKV / 128, T / 128, 2), 256, 0, stream>>>(
      hid_h, hid_l, wq_h, wq_l, qkv, T, C_NQKV, C_HID, C_HID / 2);
  k_normrope<<<(T * 32) / 4, 256, 0, stream>>>(qkv, tab, qnw, knw, q_h, q_l, k_h, k_l, v_h, v_l, T);
  k_flash<<<(T / 16) * C_NH, 256, 0, stream>>>(q_h, q_l, k_h, k_l, v_h, v_l, at_h, at_l, T);
  // out-proj: M=2048 N=2048 K=2048, split-K=4 -> 1024 blocks
  k_gemm_x3<<<dim3(C_HID / 128, T / 128, 4), 256, 0, stream>>>(
      at_h, at_l, wo_h, wo_l, out, T, C_HID, C_HID, C_HID / 4);
}

// Round 4
// 510.092 us; speedup vs baseline: 1.4749x; 1.4749x over previous
//
#include <hip/hip_runtime.h>
#include <cstdint>
#include <cstddef>

// MossVLSelfAttention fused pipeline, MI355X round 3 (resubmit — round 3 bench
// never ran: GPU acquisition timeout).
// Changes vs round 2:
//  - k_flash v4: LDS-staged, GQA-shared. Block=512thr/8 waves: 2 q-heads of one
//    kv-pair x 64 rows (R_eff=128 rows per staged tile). KVBLK=64, K and V^T in
//    swizzled LDS (16-chunk XOR, staged via global_load_lds with pre-swizzled
//    per-lane GLOBAL src), double-buffered, 1 barrier/tile, stage(t+1) issued
//    before compute(t). Per-wave-owned rows -> no merge phase.
//  - k_gemm_x3: split-K/atomicAdd/memsets REMOVED (33M atomics were toxic).
// Precision unchanged: bf16x3 everywhere, fp32 softmax/accum.
// Workspace layout (byte offsets, ~146 MB): same as round 2.

#define C_NH 16
#define C_NKV 8
#define C_DH 128
#define C_HID 2048
#define C_NQKV 4096
#define KVB 64

typedef unsigned short u16;
typedef __attribute__((ext_vector_type(8))) short short8;
typedef __attribute__((ext_vector_type(4))) float f32x4;

__device__ __forceinline__ u16 f2bf(float x) {
  uint32_t u = __float_as_uint(x);
  u += 0x7FFFu + ((u >> 16) & 1u);   // round-to-nearest-even
  return (u16)(u >> 16);
}
__device__ __forceinline__ float bf2f(u16 h) {
  return __uint_as_float(((uint32_t)h) << 16);
}
__device__ __forceinline__ void bsplit(float x, u16& hi, u16& lo) {
  u16 h = f2bf(x);
  hi = h;
  lo = f2bf(x - bf2f(h));             // residual: ~16 mantissa bits total
}

// async global->LDS, 16B/lane; LDS dest = wave-uniform base + lane*16.
__device__ __forceinline__ void gload16(const void* g, void* l) {
  __builtin_amdgcn_global_load_lds(
      (const __attribute__((address_space(1))) void*)g,
      (__attribute__((address_space(3))) void*)l, 16, 0, 0);
}

// ---------------- trig table ---------------------------------------------------
__global__ void k_trig(const int* __restrict__ pos, float2* __restrict__ tab) {
  int t = blockIdx.x;
  int j = threadIdx.x;                // 64 threads
  float inv = 1.0f / powf(1.0e6f, (float)j * (1.0f / 64.0f));
  float ang = (float)pos[t] * inv;
  tab[t * 64 + j] = make_float2(cosf(ang), sinf(ang));
}

// ---------------- plain split: f32[n] -> hi/lo bf16 ---------------------------
struct __align__(8) U4 { u16 a, b, c, d; };

__global__ void k_split(const float* __restrict__ in, u16* __restrict__ hi,
                        u16* __restrict__ lo, int n) {
  int i = (blockIdx.x * 256 + threadIdx.x) * 4;
  if (i >= n) return;
  float4 x = *(const float4*)(in + i);
  U4 hv, lv;
  bsplit(x.x, hv.a, lv.a);
  bsplit(x.y, hv.b, lv.b);
  bsplit(x.z, hv.c, lv.c);
  bsplit(x.w, hv.d, lv.d);
  *(U4*)(hi + i) = hv;
  *(U4*)(lo + i) = lv;
}

// ---------------- split + transpose: in[K][N] -> hi/lo[N][K] ------------------
__global__ void k_split_tr(const float* __restrict__ in, u16* __restrict__ hi,
                           u16* __restrict__ lo, int K, int N) {
  __shared__ float t[64][65];
  const int kb = blockIdx.y * 64, nb = blockIdx.x * 64;
  const int tid = threadIdx.x;
  for (int i = tid; i < 4096; i += 256) {
    int r = i >> 6, c = i & 63;
    t[r][c] = in[(size_t)(kb + r) * N + nb + c];
  }
  __syncthreads();
  for (int i = tid; i < 4096; i += 256) {
    int r = i >> 6, c = i & 63;       // r = n-local, c = k-local
    u16 h, l;
    bsplit(t[c][r], h, l);
    size_t o = (size_t)(nb + r) * K + kb + c;
    hi[o] = h;
    lo[o] = l;
  }
}

// ---------------- bf16x3 GEMM: C[M][N] = A[M][K] * B^T[N][K] ------------------
// m97 structure: 128x128 tile, 4 waves, BK=32, single-buffer LDS staged via
// global_load_lds width=16, 2 barriers per K-step. No split-K, plain stores.
__global__ __launch_bounds__(256, 2)
void k_gemm_x3(const u16* __restrict__ Ah, const u16* __restrict__ Al,
               const u16* __restrict__ Bh, const u16* __restrict__ Bl,
               float* __restrict__ C, int M, int N, int K) {
  __shared__ u16 lds[4][4096];          // [Ah,Al,Bh,Bl][128 rows x 32 k]
  const int tid = threadIdx.x;
  const int lane = tid & 63;
  const int wv = tid >> 6;
  const int wr = wv >> 1, wc = wv & 1;
  const int mb = blockIdx.y * 128, nb = blockIdx.x * 128;
  const int ra = lane & 15, ko = (lane >> 4) * 8;

  f32x4 acc[4][4] = {};
  const int nk = K >> 5;
  const int rS = lane >> 2, cS = (lane & 3) * 8;   // staging row/col in chunk

  for (int kt = 0; kt < nk; ++kt) {
    const int kb = kt * 32;
    __syncthreads();                    // previous compute done, LDS reusable
#pragma unroll
    for (int ci = 0; ci < 2; ++ci) {    // wave stages chunks 2w, 2w+1 (16 rows)
      int c = wv * 2 + ci;
      int row = c * 16 + rS;
      gload16(Ah + (size_t)(mb + row) * K + kb + cS, &lds[0][c * 512]);
      gload16(Al + (size_t)(mb + row) * K + kb + cS, &lds[1][c * 512]);
      gload16(Bh + (size_t)(nb + row) * K + kb + cS, &lds[2][c * 512]);
      gload16(Bl + (size_t)(nb + row) * K + kb + cS, &lds[3][c * 512]);
    }
    __syncthreads();                    // drains vmcnt before barrier

    short8 a_h[4], a_l[4], b_h[4], b_l[4];
#pragma unroll
    for (int m = 0; m < 4; ++m) {
      int r = (wr * 64 + m * 16 + ra) * 32 + ko;
      a_h[m] = *(const short8*)&lds[0][r];
      a_l[m] = *(const short8*)&lds[1][r];
    }
#pragma unroll
    for (int n = 0; n < 4; ++n) {
      int r = (wc * 64 + n * 16 + ra) * 32 + ko;
      b_h[n] = *(const short8*)&lds[2][r];
      b_l[n] = *(const short8*)&lds[3][r];
    }
#pragma unroll
    for (int m = 0; m < 4; ++m)
#pragma unroll
      for (int n = 0; n < 4; ++n) {
        acc[m][n] = __builtin_amdgcn_mfma_f32_16x16x32_bf16(a_h[m], b_h[n], acc[m][n], 0, 0, 0);
        acc[m][n] = __builtin_amdgcn_mfma_f32_16x16x32_bf16(a_h[m], b_l[n], acc[m][n], 0, 0, 0);
        acc[m][n] = __builtin_amdgcn_mfma_f32_16x16x32_bf16(a_l[m], b_h[n], acc[m][n], 0, 0, 0);
      }
  }
  const int cr = mb + wr * 64 + (lane >> 4) * 4;
  const int cc = nb + wc * 64 + ra;
#pragma unroll
  for (int m = 0; m < 4; ++m)
#pragma unroll
    for (int n = 0; n < 4; ++n)
#pragma unroll
      for (int r = 0; r < 4; ++r)
        C[(size_t)(cr + m * 16 + r) * N + cc + n * 16] = acc[m][n][r];
}

// ---------------- RMSNorm + RoPE + split (q,k) / split+transpose (v) ----------
__global__ void k_normrope(const float* __restrict__ qkv, const float2* __restrict__ tab,
                           const float* __restrict__ qw, const float* __restrict__ kw,
                           u16* __restrict__ Qh, u16* __restrict__ Ql,
                           u16* __restrict__ Kh, u16* __restrict__ Kl,
                           u16* __restrict__ Vh, u16* __restrict__ Vl, int T) {
  int gw = blockIdx.x * 4 + (threadIdx.x >> 6);
  if (gw >= T * 32) return;
  int lane = threadIdx.x & 63;
  int t = gw >> 5, hd = gw & 31;
  const float* src;
  if (hd < C_NH)              src = qkv + (size_t)t * C_NQKV + hd * C_DH;
  else if (hd < C_NH + C_NKV) src = qkv + (size_t)t * C_NQKV + C_NH * C_DH + (hd - C_NH) * C_DH;
  else                        src = qkv + (size_t)t * C_NQKV + (C_NH + C_NKV) * C_DH + (hd - C_NH - C_NKV) * C_DH;
  float x1 = src[lane], x2 = src[lane + 64];

  if (hd >= C_NH + C_NKV) {   // v: split + store transposed [8][128][T]
    int vh = hd - C_NH - C_NKV;
    u16 h, l;
    bsplit(x1, h, l);
    size_t o1 = ((size_t)vh * C_DH + lane) * T + t;
    Vh[o1] = h; Vl[o1] = l;
    bsplit(x2, h, l);
    size_t o2 = ((size_t)vh * C_DH + lane + 64) * T + t;
    Vh[o2] = h; Vl[o2] = l;
    return;
  }
  float ss = x1 * x1 + x2 * x2;
  ss += __shfl_xor(ss, 1, 64);
  ss += __shfl_xor(ss, 2, 64);
  ss += __shfl_xor(ss, 4, 64);
  ss += __shfl_xor(ss, 8, 64);
  ss += __shfl_xor(ss, 16, 64);
  ss += __shfl_xor(ss, 32, 64);
  float rms = rsqrtf(ss * (1.0f / 128.0f) + 1e-6f);
  const float* w = (hd < C_NH) ? qw : kw;
  float y1 = x1 * rms * w[lane];
  float y2 = x2 * rms * w[lane + 64];
  float2 cs = tab[t * 64 + lane];
  float o1 = y1 * cs.x - y2 * cs.y;
  float o2 = y2 * cs.x + y1 * cs.y;
  u16 h, l;
  if (hd < C_NH) {
    size_t o = ((size_t)t * C_NH + hd) * C_DH + lane;
    bsplit(o1, h, l); Qh[o] = h; Ql[o] = l;
    bsplit(o2, h, l); Qh[o + 64] = h; Ql[o + 64] = l;
  } else {
    int kh = hd - C_NH;
    size_t o = ((size_t)t * C_NKV + kh) * C_DH + lane;
    bsplit(o1, h, l); Kh[o] = h; Kl[o] = l;
    bsplit(o2, h, l); Kh[o + 64] = h; Kl[o + 64] = l;
  }
}

// ---------------- causal flash attention v4 (LDS-staged, GQA-shared) ----------
// Grid 256 blocks: hk = blk&7 (XCD pin), qt = blk>>3 (0..31). Block 512 thr:
// waves 0-3 -> head 2hk, waves 4-7 -> head 2hk+1; wave owns 16 q-rows of the
// shared 64-row q-tile. K tile [64][128] and V tile [64][128] (logical
// (r=d&63, c=(d>>6)*8+keychunk)) both 16-chunk XOR-swizzled in LDS,
// double-buffered, staged with global_load_lds from pre-swizzled global src.
__global__ __launch_bounds__(512, 2)
void k_flash(const u16* __restrict__ Qh, const u16* __restrict__ Ql,
             const u16* __restrict__ Kg_h, const u16* __restrict__ Kg_l,
             const u16* __restrict__ Vg_h, const u16* __restrict__ Vg_l,
             u16* __restrict__ Oh, u16* __restrict__ Ol, int T) {
  __shared__ u16 KV[2][4][KVB * C_DH];   // [buf][Kh,Kl,Vh,Vl] = 128 KiB
  __shared__ u16 Pex[8][2][16 * 36];     // per-wave P hi/lo, pad 36 = 18 KiB
  const int tid = threadIdx.x, lane = tid & 63, wv = tid >> 6;
  const int lm = lane & 15, lq = lane >> 4;
  const int hk = blockIdx.x & 7, qt = blockIdx.x >> 3;
  const int wq = wv & 3, wh = wv >> 2;
  const int h = hk * 2 + wh;
  const int row16 = qt * 64 + wq * 16;      // wave's 16-row base (global)

  // ---- Q fragments in registers for the whole kernel ----
  short8 qfh[4], qfl[4];
#pragma unroll
  for (int kc = 0; kc < 4; ++kc) {
    size_t o = ((size_t)(row16 + lm) * C_NH + h) * C_DH + kc * 32 + lq * 8;
    qfh[kc] = *(const short8*)(Qh + o);
    qfl[kc] = *(const short8*)(Ql + o);
  }
  f32x4 o_acc[8] = {};
  float m_r[4], l_r[4];
#pragma unroll
  for (int r = 0; r < 4; ++r) { m_r[r] = -1e30f; l_r[r] = 0.f; }

  // ---- staging: wave (wv>>1) owns array, (wv&1) owns half; 8x 1KB loads ----
  const int s_arr = wv >> 1, s_hf = wv & 1;
  const int s_rr = lane >> 4, s_ph = lane & 15;
  auto stage = [&](int buf, int kt) {
    const int kvb = kt * KVB;
#pragma unroll
    for (int j = 0; j < 8; ++j) {
      const int r0 = s_hf * 32 + j * 4;
      const int r = r0 + s_rr;
      const int c = s_ph ^ (r & 15);          // logical chunk (pre-swizzled src)
      const u16* g;
      if (s_arr < 2) {                         // K: [key][128] rows
        const u16* base = (s_arr == 0) ? Kg_h : Kg_l;
        g = base + ((size_t)(kvb + r) * C_NKV + hk) * C_DH + c * 8;
      } else {                                 // V: logical (r=d&63, c=(d>>6)*8+kc)
        const int d = r + ((c >> 3) << 6);
        const u16* base = (s_arr == 2) ? Vg_h : Vg_l;
        g = base + ((size_t)hk * C_DH + d) * T + kvb + (c & 7) * 8;
      }
      gload16(g, &KV[buf][s_arr][r0 * C_DH]);
    }
  };

  const float scale = 0.08838834764831845f;   // 1/sqrt(128)
  const int ntiles = qt + 1;

  stage(0, 0);
  __syncthreads();

  for (int kt = 0; kt < ntiles; ++kt) {
    const int buf = kt & 1;
    const int kvb = kt * KVB;
    if (kt + 1 < ntiles) stage(buf ^ 1, kt + 1);   // loads fly under compute

    // ---- S = Q K^T (swizzled LDS reads) ----
    f32x4 s[4] = {};
#pragma unroll
    for (int nt = 0; nt < 4; ++nt) {
      const int krow = nt * 16 + lm;
#pragma unroll
      for (int kc = 0; kc < 4; ++kc) {
        const int phys = (kc * 4 + lq) ^ lm;       // (row&15)==lm
        short8 bh = *(const short8*)&KV[buf][0][krow * C_DH + phys * 8];
        short8 bl = *(const short8*)&KV[buf][1][krow * C_DH + phys * 8];
        s[nt] = __builtin_amdgcn_mfma_f32_16x16x32_bf16(qfh[kc], bh, s[nt], 0, 0, 0);
        s[nt] = __builtin_amdgcn_mfma_f32_16x16x32_bf16(qfh[kc], bl, s[nt], 0, 0, 0);
        s[nt] = __builtin_amdgcn_mfma_f32_16x16x32_bf16(qfl[kc], bh, s[nt], 0, 0, 0);
      }
    }

    // ---- online softmax (per-wave-owned rows, 16-lane reduce) ----
    float p[4][4];                                  // [nt][r]
#pragma unroll
    for (int r = 0; r < 4; ++r) {
      const int qrow = row16 + lq * 4 + r;
      float sv[4];
#pragma unroll
      for (int nt = 0; nt < 4; ++nt)
        sv[nt] = (kvb + nt * 16 + lm <= qrow) ? s[nt][r] * scale : -1e30f;
      float pm = fmaxf(fmaxf(sv[0], sv[1]), fmaxf(sv[2], sv[3]));
      pm = fmaxf(pm, __shfl_xor(pm, 1, 16));
      pm = fmaxf(pm, __shfl_xor(pm, 2, 16));
      pm = fmaxf(pm, __shfl_xor(pm, 4, 16));
      pm = fmaxf(pm, __shfl_xor(pm, 8, 16));
      float mn = fmaxf(m_r[r], pm);
      float alpha = __expf(m_r[r] - mn);
      float ps = 0.f;
#pragma unroll
      for (int nt = 0; nt < 4; ++nt) { p[nt][r] = __expf(sv[nt] - mn); ps += p[nt][r]; }
      ps += __shfl_xor(ps, 1, 16);
      ps += __shfl_xor(ps, 2, 16);
      ps += __shfl_xor(ps, 4, 16);
      ps += __shfl_xor(ps, 8, 16);
      l_r[r] = l_r[r] * alpha + ps;
      m_r[r] = mn;
#pragma unroll
      for (int jb = 0; jb < 8; ++jb) o_acc[jb][r] *= alpha;
    }

    // ---- O += P V in two 32-key halves (wave-local P exchange) ----
#pragma unroll
    for (int half = 0; half < 2; ++half) {
#pragma unroll
      for (int r = 0; r < 4; ++r)
#pragma unroll
        for (int t2 = 0; t2 < 2; ++t2) {
          u16 ph, pl;
          bsplit(p[half * 2 + t2][r], ph, pl);
          Pex[wv][0][(lq * 4 + r) * 36 + t2 * 16 + lm] = ph;
          Pex[wv][1][(lq * 4 + r) * 36 + t2 * 16 + lm] = pl;
        }
      short8 pah = *(const short8*)&Pex[wv][0][lm * 36 + lq * 8];
      short8 pal = *(const short8*)&Pex[wv][1][lm * 36 + lq * 8];
#pragma unroll
      for (int jb = 0; jb < 8; ++jb) {
        const int phys = (((jb >> 2) << 3) + half * 4 + lq) ^ lm;  // (r&15)==lm
        const int roff = ((jb * 16 + lm) & 63) * C_DH + phys * 8;
        short8 vh = *(const short8*)&KV[buf][2][roff];
        short8 vl = *(const short8*)&KV[buf][3][roff];
        o_acc[jb] = __builtin_amdgcn_mfma_f32_16x16x32_bf16(pah, vh, o_acc[jb], 0, 0, 0);
        o_acc[jb] = __builtin_amdgcn_mfma_f32_16x16x32_bf16(pah, vl, o_acc[jb], 0, 0, 0);
        o_acc[jb] = __builtin_amdgcn_mfma_f32_16x16x32_bf16(pal, vh, o_acc[jb], 0, 0, 0);
      }
    }
    __syncthreads();      // all waves done with buf; stage(kt+1) landed
  }

  // ---- epilogue: O /= l, split to bf16 hi/lo ----
#pragma unroll
  for (int r = 0; r < 4; ++r) {
    float inv = 1.0f / l_r[r];
    int qrow = row16 + lq * 4 + r;
#pragma unroll
    for (int jb = 0; jb < 8; ++jb) {
      float val = o_acc[jb][r] * inv;
      u16 hh, ll;
      bsplit(val, hh, ll);
      size_t oo = ((size_t)qrow * C_NH + h) * C_DH + jb * 16 + lm;
      Oh[oo] = hh;
      Ol[oo] = ll;
    }
  }
}

// ---------------- launch --------------------------------------------------------
extern "C" void kernel_launch(void* const* d_in, const int* in_sizes, int n_in,
                              void* d_out, int out_size, void* d_ws, size_t ws_size,
                              hipStream_t stream) {
  const int*   pos  = (const int*)d_in[0];
  const float* hid  = (const float*)d_in[1];
  const float* wqkv = (const float*)d_in[2];
  const float* qnw  = (const float*)d_in[3];
  const float* knw  = (const float*)d_in[4];
  const float* wo   = (const float*)d_in[5];
  float* out = (float*)d_out;
  const int T = in_sizes[0];                   // 2048

  char* ws = (char*)d_ws;
  const size_t MB = 1024 * 1024;
  u16*    hid_h = (u16*)(ws);
  u16*    hid_l = (u16*)(ws + 8 * MB);
  u16*    wq_h  = (u16*)(ws + 16 * MB);
  u16*    wq_l  = (u16*)(ws + 32 * MB);
  u16*    wo_h  = (u16*)(ws + 48 * MB);
  u16*    wo_l  = (u16*)(ws + 56 * MB);
  float*  qkv   = (float*)(ws + 64 * MB);
  u16*    q_h   = (u16*)(ws + 96 * MB);
  u16*    q_l   = (u16*)(ws + 104 * MB);
  u16*    k_h   = (u16*)(ws + 112 * MB);
  u16*    k_l   = (u16*)(ws + 116 * MB);
  u16*    v_h   = (u16*)(ws + 120 * MB);
  u16*    v_l   = (u16*)(ws + 124 * MB);
  u16*    at_h  = (u16*)(ws + 128 * MB);
  u16*    at_l  = (u16*)(ws + 136 * MB);
  float2* tab   = (float2*)(ws + 144 * MB);

  k_trig<<<T, 64, 0, stream>>>(pos, tab);
  k_split<<<(T * C_HID) / 1024, 256, 0, stream>>>(hid, hid_h, hid_l, T * C_HID);
  k_split_tr<<<dim3(C_NQKV / 64, C_HID / 64), 256, 0, stream>>>(wqkv, wq_h, wq_l, C_HID, C_NQKV);
  k_split_tr<<<dim3(C_HID / 64, C_HID / 64), 256, 0, stream>>>(wo, wo_h, wo_l, C_HID, C_HID);
  k_gemm_x3<<<dim3(C_NQKV / 128, T / 128), 256, 0, stream>>>(
      hid_h, hid_l, wq_h, wq_l, qkv, T, C_NQKV, C_HID);
  k_normrope<<<(T * 32) / 4, 256, 0, stream>>>(qkv, tab, qnw, knw, q_h, q_l, k_h, k_l, v_h, v_l, T);
  k_flash<<<T / 64 * C_NKV, 512, 0, stream>>>(q_h, q_l, k_h, k_l, v_h, v_l, at_h, at_l, T);
  k_gemm_x3<<<dim3(C_HID / 128, T / 128), 256, 0, stream>>>(
      at_h, at_l, wo_h, wo_l, out, T, C_HID, C_HID);
}